// Round 3
// baseline (1046.684 us; speedup 1.0000x reference)
//
#include <hip/hip_runtime.h>
#include <hip/hip_bf16.h>

// GQNN: 2-layer GraphSAGE (mean aggr) + fc head. N=100k, E=3.2M, d=64/65.
// R3: layer gathers restructured to float4 group loads. R2 evidence: k_layer1
// 267us with only 3.1 TB/s L1-demand / 22% VALU / 0 Mfma => latency-bound on
// gather instruction count (34 mem-instrs/node, ~4 outstanding). Now 64 lanes
// = 4 groups x 16 lanes, one instr loads 4 whole rows (1KB), 2 accumulators
// => ~10 mem-instrs/node, 2+ KB in flight per wave. Build kernels unchanged.

#define WAVES_PER_BLOCK 16
#define LAYER_BLOCK (WAVES_PER_BLOCK * 64)
#define LAYER_GRID 512

#define BSH 7                    // bucket shift: 128 nodes per bucket
#define NBKT 782                 // ceil(100000 / 128)
#define NBLK 256                 // binning blocks

// ---------------- CSR build (unchanged from R2) ----------------

__global__ __launch_bounds__(256) void k_hist(const int* __restrict__ dst,
                                              int* __restrict__ histT, int E) {
    __shared__ int h[NBKT];
    for (int i = threadIdx.x; i < NBKT; i += 256) h[i] = 0;
    __syncthreads();
    int per = (E + NBLK - 1) / NBLK;
    int lo = blockIdx.x * per;
    int hi = lo + per; if (hi > E) hi = E;
    for (int e = lo + threadIdx.x; e < hi; e += 256)
        atomicAdd(&h[dst[e] >> BSH], 1);
    __syncthreads();
    for (int k = threadIdx.x; k < NBKT; k += 256)
        histT[k * NBLK + blockIdx.x] = h[k];
}

__global__ __launch_bounds__(NBLK) void k_scanblk(int* __restrict__ histT,
                                                  int* __restrict__ btot) {
    __shared__ int s[NBLK];
    int k = blockIdx.x, t = threadIdx.x;
    int v = histT[k * NBLK + t];
    s[t] = v;
    __syncthreads();
    for (int off = 1; off < NBLK; off <<= 1) {
        int u = (t >= off) ? s[t - off] : 0;
        __syncthreads();
        s[t] += u;
        __syncthreads();
    }
    histT[k * NBLK + t] = s[t] - v;
    if (t == NBLK - 1) btot[k] = s[t];
}

__global__ __launch_bounds__(1024) void k_scanbkt(const int* __restrict__ btot,
                                                  int* __restrict__ bstart) {
    __shared__ int s[1024];
    int t = threadIdx.x;
    int v = (t < NBKT) ? btot[t] : 0;
    s[t] = v;
    __syncthreads();
    for (int off = 1; off < 1024; off <<= 1) {
        int u = (t >= off) ? s[t - off] : 0;
        __syncthreads();
        s[t] += u;
        __syncthreads();
    }
    if (t < NBKT) bstart[t] = s[t] - v;
    if (t == NBKT - 1) bstart[NBKT] = s[t];
}

__global__ __launch_bounds__(256) void k_scatter(const int* __restrict__ src,
                                                 const int* __restrict__ dst,
                                                 const int* __restrict__ histT,
                                                 const int* __restrict__ bstart,
                                                 int* __restrict__ binned, int E) {
    __shared__ int cur[NBKT];
    int b = blockIdx.x;
    for (int k = threadIdx.x; k < NBKT; k += 256)
        cur[k] = bstart[k] + histT[k * NBLK + b];
    __syncthreads();
    int per = (E + NBLK - 1) / NBLK;
    int lo = b * per;
    int hi = lo + per; if (hi > E) hi = E;
    for (int e = lo + threadIdx.x; e < hi; e += 256) {
        int d = dst[e], s = src[e];
        int pos = atomicAdd(&cur[d >> BSH], 1);
        binned[pos] = (s << BSH) | (d & ((1 << BSH) - 1));
    }
}

__global__ __launch_bounds__(256) void k_bucket(const int* __restrict__ binned,
                                                const int* __restrict__ bstart,
                                                int* __restrict__ rowptr,
                                                int* __restrict__ deg,
                                                int* __restrict__ colidx, int N) {
    __shared__ int cnt[128], sc[128], cur[128];
    int k = blockIdx.x, t = threadIdx.x;
    int lo = bstart[k], hi = bstart[k + 1];
    if (t < 128) cnt[t] = 0;
    __syncthreads();
    for (int e = lo + t; e < hi; e += 256)
        atomicAdd(&cnt[binned[e] & 127], 1);
    __syncthreads();
    if (t < 128) sc[t] = cnt[t];
    __syncthreads();
    for (int off = 1; off < 128; off <<= 1) {
        int u = 0;
        if (t < 128 && t >= off) u = sc[t - off];
        __syncthreads();
        if (t < 128) sc[t] += u;
        __syncthreads();
    }
    if (t < 128) {
        int abs0 = lo + (sc[t] - cnt[t]);
        cur[t] = abs0;
        int gnode = (k << BSH) + t;
        if (gnode < N) { rowptr[gnode] = abs0; deg[gnode] = cnt[t]; }
    }
    __syncthreads();
    for (int e = lo + t; e < hi; e += 256) {
        int p = binned[e];
        int pos = atomicAdd(&cur[p & 127], 1);
        colidx[pos] = p >> BSH;
    }
}

// ---------------- Layers (R3: float4 grouped gathers) ----------------
// Wave = 4 groups x 16 lanes. grp = lane>>4 takes neighbor (j*8 + grp) and
// (j*8 + 4 + grp); sub = lane&15 covers columns [4*sub, 4*sub+4).

// Layer 1: h1 = relu(mean([x|tau][nbrs]) @ W1l + [x|tau] @ W1r + b1l)
__global__ __launch_bounds__(LAYER_BLOCK) void k_layer1(
    const float* __restrict__ x, const float* __restrict__ tau,
    const int* __restrict__ rowptr, const int* __restrict__ deg,
    const int* __restrict__ colidx,
    const float* __restrict__ W1l, const float* __restrict__ b1l,
    const float* __restrict__ W1r, float* __restrict__ h1, int N) {
    __shared__ float sW[65 * 64 * 2];
    for (int i = threadIdx.x; i < 65 * 64 * 2; i += LAYER_BLOCK)
        sW[i] = (i < 65 * 64) ? W1l[i] : W1r[i - 65 * 64];
    __syncthreads();
    const float* sWl = sW;
    const float* sWr = sW + 65 * 64;

    int lane = threadIdx.x & 63;
    int grp = lane >> 4;
    int sub = lane & 15;
    int wave = blockIdx.x * WAVES_PER_BLOCK + (threadIdx.x >> 6);
    int nwaves = gridDim.x * WAVES_PER_BLOCK;

    float bl = b1l[lane];
    float wl_tau = sWl[64 * 64 + lane];
    float wr_tau = sWr[64 * 64 + lane];

    for (int node = wave; node < N; node += nwaves) {
        int start = rowptr[node];
        int d = deg[node];
        float4 acc0 = {0.f, 0.f, 0.f, 0.f};
        float4 acc1 = {0.f, 0.f, 0.f, 0.f};
        float sumtau = 0.f;
        for (int base = 0; base < d; base += 64) {
            int n = d - base;
            if (n > 64) n = 64;
            int sidx = 0;
            if (lane < n) {
                sidx = colidx[start + base + lane];
                sumtau += tau[sidx];
            }
            int full = n & ~7;
            for (int j = 0; j < full; j += 8) {
                int a0 = __shfl(sidx, j + grp, 64);
                int a1 = __shfl(sidx, j + 4 + grp, 64);
                const float4 v0 = *(const float4*)(x + (size_t)a0 * 64 + sub * 4);
                const float4 v1 = *(const float4*)(x + (size_t)a1 * 64 + sub * 4);
                acc0.x += v0.x; acc0.y += v0.y; acc0.z += v0.z; acc0.w += v0.w;
                acc1.x += v1.x; acc1.y += v1.y; acc1.z += v1.z; acc1.w += v1.w;
            }
            int rem = n - full;
            if (rem) {
                int j0 = full + grp, j1 = full + 4 + grp;
                int i0 = (j0 < n) ? j0 : n - 1;
                int i1 = (j1 < n) ? j1 : n - 1;
                int a0 = __shfl(sidx, i0, 64);
                int a1 = __shfl(sidx, i1, 64);
                const float4 v0 = *(const float4*)(x + (size_t)a0 * 64 + sub * 4);
                const float4 v1 = *(const float4*)(x + (size_t)a1 * 64 + sub * 4);
                if (j0 < n) { acc0.x += v0.x; acc0.y += v0.y; acc0.z += v0.z; acc0.w += v0.w; }
                if (j1 < n) { acc1.x += v1.x; acc1.y += v1.y; acc1.z += v1.z; acc1.w += v1.w; }
            }
        }
        acc0.x += acc1.x; acc0.y += acc1.y; acc0.z += acc1.z; acc0.w += acc1.w;
        // fold the 4 groups: lanes g*16+sub all end with the full column sums
#pragma unroll
        for (int m = 16; m <= 32; m <<= 1) {
            acc0.x += __shfl_xor(acc0.x, m, 64);
            acc0.y += __shfl_xor(acc0.y, m, 64);
            acc0.z += __shfl_xor(acc0.z, m, 64);
            acc0.w += __shfl_xor(acc0.w, m, 64);
        }
#pragma unroll
        for (int off = 32; off > 0; off >>= 1) sumtau += __shfl_down(sumtau, off, 64);
        sumtau = __shfl(sumtau, 0, 64);

        float inv = 1.f / fmaxf((float)d, 1.f);
        float mv[4] = {acc0.x * inv, acc0.y * inv, acc0.z * inv, acc0.w * inv};
        float mtau = sumtau * inv;
        float xi = x[(size_t)node * 64 + lane];
        float ti = tau[node];

        float acc = bl + mtau * wl_tau + ti * wr_tau;
#pragma unroll
        for (int k = 0; k < 64; ++k) {
            float mk = __shfl(mv[k & 3], k >> 2, 64);
            float xk = __shfl(xi, k, 64);
            acc = fmaf(mk, sWl[k * 64 + lane], acc);
            acc = fmaf(xk, sWr[k * 64 + lane], acc);
        }
        h1[(size_t)node * 64 + lane] = fmaxf(acc, 0.f);
    }
}

// Layer 2 + fc head
__global__ __launch_bounds__(LAYER_BLOCK) void k_layer2(
    const float* __restrict__ h1,
    const int* __restrict__ rowptr, const int* __restrict__ deg,
    const int* __restrict__ colidx,
    const float* __restrict__ W2l, const float* __restrict__ b2l,
    const float* __restrict__ W2r, const float* __restrict__ Wfc,
    const float* __restrict__ bfc, float* __restrict__ out, int N) {
    __shared__ float sW[64 * 64 * 2 + 64];
    for (int i = threadIdx.x; i < 64 * 64 * 2; i += LAYER_BLOCK)
        sW[i] = (i < 64 * 64) ? W2l[i] : W2r[i - 64 * 64];
    if (threadIdx.x < 64) sW[64 * 64 * 2 + threadIdx.x] = Wfc[threadIdx.x];
    __syncthreads();
    const float* sWl = sW;
    const float* sWr = sW + 64 * 64;
    const float* sWfc = sW + 64 * 64 * 2;

    int lane = threadIdx.x & 63;
    int grp = lane >> 4;
    int sub = lane & 15;
    int wave = blockIdx.x * WAVES_PER_BLOCK + (threadIdx.x >> 6);
    int nwaves = gridDim.x * WAVES_PER_BLOCK;

    float bl = b2l[lane];
    float wfc = sWfc[lane];
    float b0 = bfc[0];

    for (int node = wave; node < N; node += nwaves) {
        int start = rowptr[node];
        int d = deg[node];
        float4 acc0 = {0.f, 0.f, 0.f, 0.f};
        float4 acc1 = {0.f, 0.f, 0.f, 0.f};
        for (int base = 0; base < d; base += 64) {
            int n = d - base;
            if (n > 64) n = 64;
            int sidx = 0;
            if (lane < n) sidx = colidx[start + base + lane];
            int full = n & ~7;
            for (int j = 0; j < full; j += 8) {
                int a0 = __shfl(sidx, j + grp, 64);
                int a1 = __shfl(sidx, j + 4 + grp, 64);
                const float4 v0 = *(const float4*)(h1 + (size_t)a0 * 64 + sub * 4);
                const float4 v1 = *(const float4*)(h1 + (size_t)a1 * 64 + sub * 4);
                acc0.x += v0.x; acc0.y += v0.y; acc0.z += v0.z; acc0.w += v0.w;
                acc1.x += v1.x; acc1.y += v1.y; acc1.z += v1.z; acc1.w += v1.w;
            }
            int rem = n - full;
            if (rem) {
                int j0 = full + grp, j1 = full + 4 + grp;
                int i0 = (j0 < n) ? j0 : n - 1;
                int i1 = (j1 < n) ? j1 : n - 1;
                int a0 = __shfl(sidx, i0, 64);
                int a1 = __shfl(sidx, i1, 64);
                const float4 v0 = *(const float4*)(h1 + (size_t)a0 * 64 + sub * 4);
                const float4 v1 = *(const float4*)(h1 + (size_t)a1 * 64 + sub * 4);
                if (j0 < n) { acc0.x += v0.x; acc0.y += v0.y; acc0.z += v0.z; acc0.w += v0.w; }
                if (j1 < n) { acc1.x += v1.x; acc1.y += v1.y; acc1.z += v1.z; acc1.w += v1.w; }
            }
        }
        acc0.x += acc1.x; acc0.y += acc1.y; acc0.z += acc1.z; acc0.w += acc1.w;
#pragma unroll
        for (int m = 16; m <= 32; m <<= 1) {
            acc0.x += __shfl_xor(acc0.x, m, 64);
            acc0.y += __shfl_xor(acc0.y, m, 64);
            acc0.z += __shfl_xor(acc0.z, m, 64);
            acc0.w += __shfl_xor(acc0.w, m, 64);
        }
        float inv = 1.f / fmaxf((float)d, 1.f);
        float mv[4] = {acc0.x * inv, acc0.y * inv, acc0.z * inv, acc0.w * inv};
        float hi = h1[(size_t)node * 64 + lane];

        float acc = bl;
#pragma unroll
        for (int k = 0; k < 64; ++k) {
            float mk = __shfl(mv[k & 3], k >> 2, 64);
            float hk = __shfl(hi, k, 64);
            acc = fmaf(mk, sWl[k * 64 + lane], acc);
            acc = fmaf(hk, sWr[k * 64 + lane], acc);
        }
        float h2 = fmaxf(acc, 0.f);
        float p = h2 * wfc;
#pragma unroll
        for (int off = 32; off > 0; off >>= 1) p += __shfl_down(p, off, 64);
        if (lane == 0) out[node] = p + b0;
    }
}

extern "C" void kernel_launch(void* const* d_in, const int* in_sizes, int n_in,
                              void* d_out, int out_size, void* d_ws, size_t ws_size,
                              hipStream_t stream) {
    const float* x   = (const float*)d_in[0];
    const int*   ei  = (const int*)d_in[1];
    const float* tau = (const float*)d_in[2];
    const float* W1l = (const float*)d_in[3];
    const float* b1l = (const float*)d_in[4];
    const float* W1r = (const float*)d_in[5];
    const float* W2l = (const float*)d_in[6];
    const float* b2l = (const float*)d_in[7];
    const float* W2r = (const float*)d_in[8];
    const float* Wfc = (const float*)d_in[9];
    const float* bfc = (const float*)d_in[10];
    float* out = (float*)d_out;

    const int N = in_sizes[0] / 64;   // 100000
    const int E = in_sizes[1] / 2;    // 3200000
    const int* src = ei;
    const int* dst = ei + E;

    char* w = (char*)d_ws;
    auto take = [&](size_t b) { char* p = w; w += (b + 255) & ~(size_t)255; return p; };
    int*   histT  = (int*)take((size_t)NBKT * NBLK * 4);
    int*   btot   = (int*)take((size_t)NBKT * 4);
    int*   bstart = (int*)take((size_t)(NBKT + 1) * 4);
    int*   binned = (int*)take((size_t)E * 4);
    int*   rowptr = (int*)take((size_t)N * 4);
    int*   deg    = (int*)take((size_t)N * 4);
    int*   colidx = (int*)take((size_t)E * 4);
    float* h1     = (float*)take((size_t)N * 64 * 4);

    k_hist   <<<NBLK, 256, 0, stream>>>(dst, histT, E);
    k_scanblk<<<NBKT, NBLK, 0, stream>>>(histT, btot);
    k_scanbkt<<<1, 1024, 0, stream>>>(btot, bstart);
    k_scatter<<<NBLK, 256, 0, stream>>>(src, dst, histT, bstart, binned, E);
    k_bucket <<<NBKT, 256, 0, stream>>>(binned, bstart, rowptr, deg, colidx, N);
    k_layer1 <<<LAYER_GRID, LAYER_BLOCK, 0, stream>>>(x, tau, rowptr, deg, colidx,
                                                      W1l, b1l, W1r, h1, N);
    k_layer2 <<<LAYER_GRID, LAYER_BLOCK, 0, stream>>>(h1, rowptr, deg, colidx,
                                                      W2l, b2l, W2r, Wfc, bfc, out, N);
}

// Round 4
// 648.467 us; speedup vs baseline: 1.6141x; 1.6141x over previous
//
#include <hip/hip_runtime.h>
#include <hip/hip_bf16.h>
#include <hip/hip_fp16.h>

// GQNN: 2-layer GraphSAGE (mean aggr) + fc head. N=100k, E=3.2M, d=64/65.
// R4: revert to R2's L2-friendly gather shape (all 64 lanes read ONE row per
// instruction, contiguous). R3's 4-rows-per-instruction float4 grouping
// collapsed L2 hit rate (FETCH 372MB -> 1.17GB) and regressed 653->1047us.
// New in R4: gather operands stored fp16 (row = 128B = one L2 line; demand
// halves, 12.8MB arrays ~fit aggregate L2) + unroll-8 (8 loads in flight).
// Self terms: layer1 uses fp32 x (sequential); precision margin ~1e-3 vs
// 8.3e-3 threshold. Build kernels unchanged from R2.

#define WAVES_PER_BLOCK 16
#define LAYER_BLOCK (WAVES_PER_BLOCK * 64)
#define LAYER_GRID 512

#define BSH 7                    // bucket shift: 128 nodes per bucket
#define NBKT 782                 // ceil(100000 / 128)
#define NBLK 256                 // binning blocks

// ---------------- CSR build (unchanged from R2) ----------------

__global__ __launch_bounds__(256) void k_hist(const int* __restrict__ dst,
                                              int* __restrict__ histT, int E) {
    __shared__ int h[NBKT];
    for (int i = threadIdx.x; i < NBKT; i += 256) h[i] = 0;
    __syncthreads();
    int per = (E + NBLK - 1) / NBLK;
    int lo = blockIdx.x * per;
    int hi = lo + per; if (hi > E) hi = E;
    for (int e = lo + threadIdx.x; e < hi; e += 256)
        atomicAdd(&h[dst[e] >> BSH], 1);
    __syncthreads();
    for (int k = threadIdx.x; k < NBKT; k += 256)
        histT[k * NBLK + blockIdx.x] = h[k];
}

__global__ __launch_bounds__(NBLK) void k_scanblk(int* __restrict__ histT,
                                                  int* __restrict__ btot) {
    __shared__ int s[NBLK];
    int k = blockIdx.x, t = threadIdx.x;
    int v = histT[k * NBLK + t];
    s[t] = v;
    __syncthreads();
    for (int off = 1; off < NBLK; off <<= 1) {
        int u = (t >= off) ? s[t - off] : 0;
        __syncthreads();
        s[t] += u;
        __syncthreads();
    }
    histT[k * NBLK + t] = s[t] - v;
    if (t == NBLK - 1) btot[k] = s[t];
}

__global__ __launch_bounds__(1024) void k_scanbkt(const int* __restrict__ btot,
                                                  int* __restrict__ bstart) {
    __shared__ int s[1024];
    int t = threadIdx.x;
    int v = (t < NBKT) ? btot[t] : 0;
    s[t] = v;
    __syncthreads();
    for (int off = 1; off < 1024; off <<= 1) {
        int u = (t >= off) ? s[t - off] : 0;
        __syncthreads();
        s[t] += u;
        __syncthreads();
    }
    if (t < NBKT) bstart[t] = s[t] - v;
    if (t == NBKT - 1) bstart[NBKT] = s[t];
}

__global__ __launch_bounds__(256) void k_scatter(const int* __restrict__ src,
                                                 const int* __restrict__ dst,
                                                 const int* __restrict__ histT,
                                                 const int* __restrict__ bstart,
                                                 int* __restrict__ binned, int E) {
    __shared__ int cur[NBKT];
    int b = blockIdx.x;
    for (int k = threadIdx.x; k < NBKT; k += 256)
        cur[k] = bstart[k] + histT[k * NBLK + b];
    __syncthreads();
    int per = (E + NBLK - 1) / NBLK;
    int lo = b * per;
    int hi = lo + per; if (hi > E) hi = E;
    for (int e = lo + threadIdx.x; e < hi; e += 256) {
        int d = dst[e], s = src[e];
        int pos = atomicAdd(&cur[d >> BSH], 1);
        binned[pos] = (s << BSH) | (d & ((1 << BSH) - 1));
    }
}

__global__ __launch_bounds__(256) void k_bucket(const int* __restrict__ binned,
                                                const int* __restrict__ bstart,
                                                int* __restrict__ rowptr,
                                                int* __restrict__ deg,
                                                int* __restrict__ colidx, int N) {
    __shared__ int cnt[128], sc[128], cur[128];
    int k = blockIdx.x, t = threadIdx.x;
    int lo = bstart[k], hi = bstart[k + 1];
    if (t < 128) cnt[t] = 0;
    __syncthreads();
    for (int e = lo + t; e < hi; e += 256)
        atomicAdd(&cnt[binned[e] & 127], 1);
    __syncthreads();
    if (t < 128) sc[t] = cnt[t];
    __syncthreads();
    for (int off = 1; off < 128; off <<= 1) {
        int u = 0;
        if (t < 128 && t >= off) u = sc[t - off];
        __syncthreads();
        if (t < 128) sc[t] += u;
        __syncthreads();
    }
    if (t < 128) {
        int abs0 = lo + (sc[t] - cnt[t]);
        cur[t] = abs0;
        int gnode = (k << BSH) + t;
        if (gnode < N) { rowptr[gnode] = abs0; deg[gnode] = cnt[t]; }
    }
    __syncthreads();
    for (int e = lo + t; e < hi; e += 256) {
        int p = binned[e];
        int pos = atomicAdd(&cur[p & 127], 1);
        colidx[pos] = p >> BSH;
    }
}

// ---------------- fp32 -> fp16 prep for x ----------------
__global__ __launch_bounds__(256) void k_prep(const float* __restrict__ x,
                                              __half* __restrict__ xh, int n2) {
    int i = blockIdx.x * 256 + threadIdx.x;
    if (i < n2) {
        float2 v = ((const float2*)x)[i];
        ((__half2*)xh)[i] = __floats2half2_rn(v.x, v.y);
    }
}

// ---------------- Layers (R2 gather shape, fp16 rows, unroll 8) ----------------

// Layer 1: h1 = relu(mean([x|tau][nbrs]) @ W1l + [x|tau] @ W1r + b1l), stored fp16
__global__ __launch_bounds__(LAYER_BLOCK) void k_layer1(
    const float* __restrict__ x, const __half* __restrict__ xh,
    const float* __restrict__ tau,
    const int* __restrict__ rowptr, const int* __restrict__ deg,
    const int* __restrict__ colidx,
    const float* __restrict__ W1l, const float* __restrict__ b1l,
    const float* __restrict__ W1r, __half* __restrict__ h1, int N) {
    __shared__ float sW[65 * 64 * 2];
    for (int i = threadIdx.x; i < 65 * 64 * 2; i += LAYER_BLOCK)
        sW[i] = (i < 65 * 64) ? W1l[i] : W1r[i - 65 * 64];
    __syncthreads();
    const float* sWl = sW;
    const float* sWr = sW + 65 * 64;

    int lane = threadIdx.x & 63;
    int wave = blockIdx.x * WAVES_PER_BLOCK + (threadIdx.x >> 6);
    int nwaves = gridDim.x * WAVES_PER_BLOCK;

    float bl = b1l[lane];
    float wl_tau = sWl[64 * 64 + lane];
    float wr_tau = sWr[64 * 64 + lane];

    for (int node = wave; node < N; node += nwaves) {
        int start = rowptr[node];
        int d = deg[node];
        float s0 = 0.f, s1 = 0.f, s2 = 0.f, s3 = 0.f;
        float s4 = 0.f, s5 = 0.f, s6 = 0.f, s7 = 0.f;
        float sumtau = 0.f;
        for (int base = 0; base < d; base += 64) {
            int n = d - base;
            if (n > 64) n = 64;
            int sidx = 0;
            if (lane < n) {
                sidx = colidx[start + base + lane];
                sumtau += tau[sidx];
            }
            int jj = 0;
            for (; jj + 8 <= n; jj += 8) {
                int a0 = __shfl(sidx, jj, 64);
                int a1 = __shfl(sidx, jj + 1, 64);
                int a2 = __shfl(sidx, jj + 2, 64);
                int a3 = __shfl(sidx, jj + 3, 64);
                int a4 = __shfl(sidx, jj + 4, 64);
                int a5 = __shfl(sidx, jj + 5, 64);
                int a6 = __shfl(sidx, jj + 6, 64);
                int a7 = __shfl(sidx, jj + 7, 64);
                s0 += __half2float(xh[(size_t)a0 * 64 + lane]);
                s1 += __half2float(xh[(size_t)a1 * 64 + lane]);
                s2 += __half2float(xh[(size_t)a2 * 64 + lane]);
                s3 += __half2float(xh[(size_t)a3 * 64 + lane]);
                s4 += __half2float(xh[(size_t)a4 * 64 + lane]);
                s5 += __half2float(xh[(size_t)a5 * 64 + lane]);
                s6 += __half2float(xh[(size_t)a6 * 64 + lane]);
                s7 += __half2float(xh[(size_t)a7 * 64 + lane]);
            }
            for (; jj < n; ++jj) {
                int a = __shfl(sidx, jj, 64);
                s0 += __half2float(xh[(size_t)a * 64 + lane]);
            }
        }
        float sum = ((s0 + s1) + (s2 + s3)) + ((s4 + s5) + (s6 + s7));
#pragma unroll
        for (int off = 32; off > 0; off >>= 1) sumtau += __shfl_down(sumtau, off, 64);
        sumtau = __shfl(sumtau, 0, 64);

        float inv = 1.f / fmaxf((float)d, 1.f);
        float mean = sum * inv;
        float mtau = sumtau * inv;
        float xi = x[(size_t)node * 64 + lane];
        float ti = tau[node];

        float acc = bl + mtau * wl_tau + ti * wr_tau;
#pragma unroll 8
        for (int k = 0; k < 64; ++k) {
            float mk = __shfl(mean, k, 64);
            float xk = __shfl(xi, k, 64);
            acc = fmaf(mk, sWl[k * 64 + lane], acc);
            acc = fmaf(xk, sWr[k * 64 + lane], acc);
        }
        h1[(size_t)node * 64 + lane] = __float2half(fmaxf(acc, 0.f));
    }
}

// Layer 2 + fc head: out = relu(mean(h1[nbrs]) @ W2l + h1 @ W2r + b2l) @ Wfc + bfc
__global__ __launch_bounds__(LAYER_BLOCK) void k_layer2(
    const __half* __restrict__ h1,
    const int* __restrict__ rowptr, const int* __restrict__ deg,
    const int* __restrict__ colidx,
    const float* __restrict__ W2l, const float* __restrict__ b2l,
    const float* __restrict__ W2r, const float* __restrict__ Wfc,
    const float* __restrict__ bfc, float* __restrict__ out, int N) {
    __shared__ float sW[64 * 64 * 2 + 64];
    for (int i = threadIdx.x; i < 64 * 64 * 2; i += LAYER_BLOCK)
        sW[i] = (i < 64 * 64) ? W2l[i] : W2r[i - 64 * 64];
    if (threadIdx.x < 64) sW[64 * 64 * 2 + threadIdx.x] = Wfc[threadIdx.x];
    __syncthreads();
    const float* sWl = sW;
    const float* sWr = sW + 64 * 64;
    const float* sWfc = sW + 64 * 64 * 2;

    int lane = threadIdx.x & 63;
    int wave = blockIdx.x * WAVES_PER_BLOCK + (threadIdx.x >> 6);
    int nwaves = gridDim.x * WAVES_PER_BLOCK;

    float bl = b2l[lane];
    float wfc = sWfc[lane];
    float b0 = bfc[0];

    for (int node = wave; node < N; node += nwaves) {
        int start = rowptr[node];
        int d = deg[node];
        float s0 = 0.f, s1 = 0.f, s2 = 0.f, s3 = 0.f;
        float s4 = 0.f, s5 = 0.f, s6 = 0.f, s7 = 0.f;
        for (int base = 0; base < d; base += 64) {
            int n = d - base;
            if (n > 64) n = 64;
            int sidx = 0;
            if (lane < n) sidx = colidx[start + base + lane];
            int jj = 0;
            for (; jj + 8 <= n; jj += 8) {
                int a0 = __shfl(sidx, jj, 64);
                int a1 = __shfl(sidx, jj + 1, 64);
                int a2 = __shfl(sidx, jj + 2, 64);
                int a3 = __shfl(sidx, jj + 3, 64);
                int a4 = __shfl(sidx, jj + 4, 64);
                int a5 = __shfl(sidx, jj + 5, 64);
                int a6 = __shfl(sidx, jj + 6, 64);
                int a7 = __shfl(sidx, jj + 7, 64);
                s0 += __half2float(h1[(size_t)a0 * 64 + lane]);
                s1 += __half2float(h1[(size_t)a1 * 64 + lane]);
                s2 += __half2float(h1[(size_t)a2 * 64 + lane]);
                s3 += __half2float(h1[(size_t)a3 * 64 + lane]);
                s4 += __half2float(h1[(size_t)a4 * 64 + lane]);
                s5 += __half2float(h1[(size_t)a5 * 64 + lane]);
                s6 += __half2float(h1[(size_t)a6 * 64 + lane]);
                s7 += __half2float(h1[(size_t)a7 * 64 + lane]);
            }
            for (; jj < n; ++jj) {
                int a = __shfl(sidx, jj, 64);
                s0 += __half2float(h1[(size_t)a * 64 + lane]);
            }
        }
        float sum = ((s0 + s1) + (s2 + s3)) + ((s4 + s5) + (s6 + s7));
        float inv = 1.f / fmaxf((float)d, 1.f);
        float mean = sum * inv;
        float hi = __half2float(h1[(size_t)node * 64 + lane]);

        float acc = bl;
#pragma unroll 8
        for (int k = 0; k < 64; ++k) {
            float mk = __shfl(mean, k, 64);
            float hk = __shfl(hi, k, 64);
            acc = fmaf(mk, sWl[k * 64 + lane], acc);
            acc = fmaf(hk, sWr[k * 64 + lane], acc);
        }
        float h2 = fmaxf(acc, 0.f);
        float p = h2 * wfc;
#pragma unroll
        for (int off = 32; off > 0; off >>= 1) p += __shfl_down(p, off, 64);
        if (lane == 0) out[node] = p + b0;
    }
}

extern "C" void kernel_launch(void* const* d_in, const int* in_sizes, int n_in,
                              void* d_out, int out_size, void* d_ws, size_t ws_size,
                              hipStream_t stream) {
    const float* x   = (const float*)d_in[0];
    const int*   ei  = (const int*)d_in[1];
    const float* tau = (const float*)d_in[2];
    const float* W1l = (const float*)d_in[3];
    const float* b1l = (const float*)d_in[4];
    const float* W1r = (const float*)d_in[5];
    const float* W2l = (const float*)d_in[6];
    const float* b2l = (const float*)d_in[7];
    const float* W2r = (const float*)d_in[8];
    const float* Wfc = (const float*)d_in[9];
    const float* bfc = (const float*)d_in[10];
    float* out = (float*)d_out;

    const int N = in_sizes[0] / 64;   // 100000
    const int E = in_sizes[1] / 2;    // 3200000
    const int* src = ei;
    const int* dst = ei + E;

    char* w = (char*)d_ws;
    auto take = [&](size_t b) { char* p = w; w += (b + 255) & ~(size_t)255; return p; };
    int*    histT  = (int*)take((size_t)NBKT * NBLK * 4);
    int*    btot   = (int*)take((size_t)NBKT * 4);
    int*    bstart = (int*)take((size_t)(NBKT + 1) * 4);
    int*    binned = (int*)take((size_t)E * 4);
    int*    rowptr = (int*)take((size_t)N * 4);
    int*    deg    = (int*)take((size_t)N * 4);
    int*    colidx = (int*)take((size_t)E * 4);
    __half* xh     = (__half*)take((size_t)N * 64 * 2);   // 12.8 MB
    __half* h1     = (__half*)take((size_t)N * 64 * 2);   // 12.8 MB

    int n2 = N * 32;  // N*64/2 half2 elements

    k_hist   <<<NBLK, 256, 0, stream>>>(dst, histT, E);
    k_scanblk<<<NBKT, NBLK, 0, stream>>>(histT, btot);
    k_scanbkt<<<1, 1024, 0, stream>>>(btot, bstart);
    k_scatter<<<NBLK, 256, 0, stream>>>(src, dst, histT, bstart, binned, E);
    k_bucket <<<NBKT, 256, 0, stream>>>(binned, bstart, rowptr, deg, colidx, N);
    k_prep   <<<(n2 + 255) / 256, 256, 0, stream>>>(x, xh, n2);
    k_layer1 <<<LAYER_GRID, LAYER_BLOCK, 0, stream>>>(x, xh, tau, rowptr, deg, colidx,
                                                      W1l, b1l, W1r, h1, N);
    k_layer2 <<<LAYER_GRID, LAYER_BLOCK, 0, stream>>>(h1, rowptr, deg, colidx,
                                                      W2l, b2l, W2r, Wfc, bfc, out, N);
}